// Round 8
// baseline (343.170 us; speedup 1.0000x reference)
//
#include <hip/hip_runtime.h>
#include <math.h>

#define N_PTS 1024
#define BATCH 8
#define KNN 20
#define EPSB 1e-5f
#define SLOPE 0.2f

typedef __attribute__((ext_vector_type(8))) short short8;
typedef __attribute__((ext_vector_type(4))) float f32x4;
typedef unsigned short ushort_t;
typedef unsigned long long u64;

__device__ __forceinline__ float lrelu(float y) { return y > 0.f ? y : SLOPE * y; }

__device__ __forceinline__ ushort_t f2bf(float f) {
    union { float f; unsigned u; } v; v.f = f;
    unsigned r = v.u + 0x7FFF + ((v.u >> 16) & 1);   // RNE
    return (ushort_t)(r >> 16);
}
__device__ __forceinline__ float bf2f(ushort_t h) {
    union { unsigned u; float f; } v; v.u = ((unsigned)h) << 16; return v.f;
}

// ---------------- weight prep ----------------
__device__ __forceinline__ void wprep_one(const float* __restrict__ w, float* __restrict__ wpt,
                                          int C, int Cout, int g) {
    int M2 = 2 * Cout;
    if (g >= C * M2) return;
    int c = g / M2, m = g - c * M2;
    float v;
    if (m < Cout) v = w[(size_t)m * 2 * C + c];
    else { int o = m - Cout; v = w[(size_t)o * 2 * C + C + c] - w[(size_t)o * 2 * C + c]; }
    wpt[(size_t)c * M2 + m] = v;
}

// W' -> bf16x3 planes, layout [m][3C] (h at +0, mid at +C, lo at +2C)
__device__ __forceinline__ void wext_one(const float* __restrict__ w, ushort_t* __restrict__ Wext,
                                         int C, int Cout, int g, int lg2C) {
    int M2 = 2 * Cout;
    if (g >= C * M2) return;
    int m = g >> lg2C, c = g & (C - 1);
    float v;
    if (m < Cout) v = w[(size_t)m * 2 * C + c];
    else { int o = m - Cout; v = w[(size_t)o * 2 * C + C + c] - w[(size_t)o * 2 * C + c]; }
    ushort_t h = f2bf(v);
    float r1 = v - bf2f(h);
    ushort_t md = f2bf(r1);
    ushort_t lo = f2bf(r1 - bf2f(md));
    ushort_t* dst = Wext + (size_t)m * 3 * C + c;
    dst[0] = h; dst[C] = md; dst[2 * C] = lo;
}

__global__ void prep_kernel(const float* __restrict__ we, ushort_t* __restrict__ weh,
                            const float* __restrict__ w0, float* __restrict__ wpt0,
                            const float* __restrict__ w1, ushort_t* __restrict__ Wext1,
                            const float* __restrict__ w2, ushort_t* __restrict__ Wext2,
                            const float* __restrict__ w3, ushort_t* __restrict__ Wext3) {
    int bx = blockIdx.x, tid = threadIdx.x;
    if (bx < 512) {
        int g = bx * 256 + tid;
        float4 v = ((const float4*)we)[g];
        ushort4 o;
        o.x = f2bf(v.x); o.y = f2bf(v.y); o.z = f2bf(v.z); o.w = f2bf(v.w);
        ((ushort4*)weh)[g] = o;
    } else if (bx < 514) {
        wprep_one(w0, wpt0, 3, 64, (bx - 512) * 256 + tid);
    } else if (bx < 546) {
        wext_one(w1, Wext1, 64, 64, (bx - 514) * 256 + tid, 6);
    } else if (bx < 610) {
        wext_one(w2, Wext2, 64, 128, (bx - 546) * 256 + tid, 6);
    } else {
        wext_one(w3, Wext3, 128, 256, (bx - 610) * 256 + tid, 7);
    }
}

// ---------------- split: fp32 [C][N] slice -> xT3 bf16 [n][3C] planes + exact fp32 xx ----------------
__global__ void __launch_bounds__(256)
split_kernel(const float* __restrict__ in, ushort_t* __restrict__ xT3,
             float* __restrict__ xxv, int C, int bstride) {
    int b = blockIdx.z, nt = blockIdx.x;
    int tid = threadIdx.x;
    __shared__ float tile[64][65];
    const float* ib = in + (size_t)b * bstride;
    int S3 = 3 * C;
    float xxa = 0.f;
    for (int ct = 0; ct < C; ct += 64) {
        __syncthreads();
        for (int qq = 0; qq < 16; qq++) {
            int e = qq * 256 + tid;
            int c = e >> 6, n = e & 63;
            tile[c][n] = ib[(size_t)(ct + c) * N_PTS + nt * 64 + n];
        }
        __syncthreads();
        if (tid < 64) {
            for (int c = 0; c < 64; c++) { float v = tile[c][tid]; xxa += v * v; }
        }
        for (int qq = 0; qq < 16; qq++) {
            int e = qq * 256 + tid;
            int n = e >> 6, c = e & 63;
            float v = tile[c][n];
            ushort_t h = f2bf(v);
            float r1 = v - bf2f(h);
            ushort_t md = f2bf(r1);
            ushort_t lo = f2bf(r1 - bf2f(md));
            ushort_t* dst = xT3 + ((size_t)b * N_PTS + nt * 64 + n) * S3 + ct + c;
            dst[0] = h; dst[C] = md; dst[2 * C] = lo;
        }
    }
    if (tid < 64) xxv[b * N_PTS + nt * 64 + tid] = xxa;
}

// ---------------- MFMA pd+abv: bf16x3 K-expansion (6 segment pairs), fp32 parity ----------------
// mt < 8 : pd tile rows n = mt*128   pd = 2*dot - xx[n] - xx[m]
// mt >= 8: abv tile rows (mt-8)*128 of W' -> A / Bv
__global__ void __launch_bounds__(256)
pdabv_mfma(const ushort_t* __restrict__ xT3, const ushort_t* __restrict__ Wext,
           const float* __restrict__ xxv,
           float* __restrict__ pd, float* __restrict__ A, float* __restrict__ Bv,
           int C, int lg2C, int Cout) {
    int b = blockIdx.z, mt = blockIdx.y, nt = blockIdx.x;
    int tid = threadIdx.x;
    int w = tid >> 6, lane = tid & 63, q = lane >> 4, lr = lane & 15;
    int mblk = w >> 1, nblk = w & 1;
    const int S3 = 3 * C;
    bool isPd = (mt < 8);
    const ushort_t* Abase = isPd ? (xT3 + ((size_t)b * N_PTS + mt * 128) * S3)
                                 : (Wext + (size_t)(mt - 8) * 128 * S3);
    const ushort_t* Bbase = xT3 + ((size_t)b * N_PTS + nt * 128) * S3;
    __shared__ __align__(16) ushort_t sA[128 * 40];
    __shared__ __align__(16) ushort_t sB[128 * 40];
    __shared__ float sxxA[128], sxxB[128];
    if (isPd && tid < 128) {
        sxxA[tid] = xxv[b * N_PTS + mt * 128 + tid];
        sxxB[tid] = xxv[b * N_PTS + nt * 128 + tid];
    }
    f32x4 acc[4][4] = {};
    int r0 = tid >> 2, s = tid & 3;
    const int pA[6] = {0, 0, 1, 1, 0, 2};   // A-side plane per segment (h,h,m,m,h,l)
    const int pB[6] = {0, 1, 0, 1, 2, 0};   // B-side plane per segment (h,m,h,m,l,h)
    for (int ks = 0; ks < 6 * C; ks += 32) {
        int seg = ks >> lg2C;
        int kl = ks & (C - 1);
        int aoff = pA[seg] * C + kl, boff = pB[seg] * C + kl;
        __syncthreads();
        for (int h = 0; h < 2; h++) {
            int r = r0 + h * 64;
            *(short8*)&sA[r * 40 + s * 8] = *(const short8*)(Abase + (size_t)r * S3 + aoff + s * 8);
            *(short8*)&sB[r * 40 + s * 8] = *(const short8*)(Bbase + (size_t)r * S3 + boff + s * 8);
        }
        __syncthreads();
        short8 af[4], bfr[4];
        for (int mi = 0; mi < 4; mi++)
            af[mi] = *(const short8*)&sA[(mblk * 64 + mi * 16 + lr) * 40 + q * 8];
        for (int ni = 0; ni < 4; ni++)
            bfr[ni] = *(const short8*)&sB[(nblk * 64 + ni * 16 + lr) * 40 + q * 8];
        for (int mi = 0; mi < 4; mi++)
            for (int ni = 0; ni < 4; ni++)
                acc[mi][ni] = __builtin_amdgcn_mfma_f32_16x16x32_bf16(af[mi], bfr[ni], acc[mi][ni], 0, 0, 0);
    }
    if (isPd) {
        for (int mi = 0; mi < 4; mi++)
        for (int r = 0; r < 4; r++) {
            int row = mblk * 64 + mi * 16 + q * 4 + r;
            float xr = sxxA[row];
            float* prow = pd + ((size_t)(b * N_PTS + mt * 128 + row)) * N_PTS + nt * 128;
            for (int ni = 0; ni < 4; ni++) {
                int col = nblk * 64 + ni * 16 + lr;
                prow[col] = 2.f * acc[mi][ni][r] - xr - sxxB[col];
            }
        }
    } else {
        for (int mi = 0; mi < 4; mi++)
        for (int r = 0; r < 4; r++) {
            int rowm = (mt - 8) * 128 + mblk * 64 + mi * 16 + q * 4 + r;
            float* dst = (rowm < Cout) ? (A + ((size_t)b * Cout + rowm) * N_PTS)
                                       : (Bv + ((size_t)b * Cout + rowm - Cout) * N_PTS);
            for (int ni = 0; ni < 4; ni++) {
                int col = nblk * 64 + ni * 16 + lr;
                dst[nt * 128 + col] = acc[mi][ni][r];
            }
        }
    }
}

// ---------------- layer-0 fused pd + abv (VALU fp32, C=3) ----------------
__global__ void __launch_bounds__(256)
pdabv_valu(const float* __restrict__ x, const float* __restrict__ wpt,
           float* __restrict__ pd, float* __restrict__ A, float* __restrict__ Bv,
           int C, int Cout, int bstride) {
    int b = blockIdx.z;
    int nt = blockIdx.y;
    int bx = blockIdx.x;
    int tid = threadIdx.x;
    int tx = tid & 15, ty = tid >> 4;
    int n0 = nt * 128;
    __shared__ float sU0[16][128];
    __shared__ float sU1[16][128];
    __shared__ float sXX[256];
    const float* xb = x + (size_t)b * bstride;
    float acc[8][8] = {};
    if (bx < 8) {
        int m0 = bx * 128;
        float xxa = 0.f;
        for (int c0 = 0; c0 < C; c0 += 16) {
            for (int q = 0; q < 2; q++) {
                int f = q * 256 + tid;
                int r = f >> 5, col = (f & 31) * 4;
                int c = c0 + r;
                float4 vn = {0.f, 0.f, 0.f, 0.f}, vm = {0.f, 0.f, 0.f, 0.f};
                if (c < C) {
                    vn = *(const float4*)&xb[(size_t)c * N_PTS + n0 + col];
                    vm = *(const float4*)&xb[(size_t)c * N_PTS + m0 + col];
                }
                *(float4*)&sU0[r][col] = vn;
                *(float4*)&sU1[r][col] = vm;
            }
            __syncthreads();
            if (tid < 128) {
                for (int k = 0; k < 16; k++) { float v = sU0[k][tid]; xxa += v * v; }
            } else {
                int u = tid - 128;
                for (int k = 0; k < 16; k++) { float v = sU1[k][u]; xxa += v * v; }
            }
            for (int k = 0; k < 16; k++) {
                float4 a0 = *(const float4*)&sU0[k][ty * 4];
                float4 a1 = *(const float4*)&sU0[k][64 + ty * 4];
                float4 b0 = *(const float4*)&sU1[k][tx * 4];
                float4 b1 = *(const float4*)&sU1[k][64 + tx * 4];
                float av[8] = {a0.x, a0.y, a0.z, a0.w, a1.x, a1.y, a1.z, a1.w};
                float bw[8] = {b0.x, b0.y, b0.z, b0.w, b1.x, b1.y, b1.z, b1.w};
                for (int i = 0; i < 8; i++)
                    for (int j = 0; j < 8; j++) acc[i][j] += av[i] * bw[j];
            }
            __syncthreads();
        }
        sXX[tid] = xxa;
        __syncthreads();
        float xnv[8], xmv[8];
        for (int i = 0; i < 8; i++) xnv[i] = sXX[(i >> 2) * 64 + ty * 4 + (i & 3)];
        for (int j = 0; j < 8; j++) xmv[j] = sXX[128 + (j >> 2) * 64 + tx * 4 + (j & 3)];
        for (int i = 0; i < 8; i++) {
            int n = n0 + (i >> 2) * 64 + ty * 4 + (i & 3);
            float* prow = pd + ((size_t)(b * N_PTS + n)) * N_PTS;
            for (int jh = 0; jh < 2; jh++) {
                float4 o;
                o.x = 2.f * acc[i][jh * 4 + 0] - xnv[i] - xmv[jh * 4 + 0];
                o.y = 2.f * acc[i][jh * 4 + 1] - xnv[i] - xmv[jh * 4 + 1];
                o.z = 2.f * acc[i][jh * 4 + 2] - xnv[i] - xmv[jh * 4 + 2];
                o.w = 2.f * acc[i][jh * 4 + 3] - xnv[i] - xmv[jh * 4 + 3];
                *(float4*)&prow[m0 + jh * 64 + tx * 4] = o;
            }
        }
    } else {
        int m0 = (bx - 8) * 128;
        int M2 = 2 * Cout;
        for (int c0 = 0; c0 < C; c0 += 16) {
            for (int q = 0; q < 2; q++) {
                int f = q * 256 + tid;
                int r = f >> 5, col = (f & 31) * 4;
                int c = c0 + r;
                float4 vw = {0.f, 0.f, 0.f, 0.f}, vx = {0.f, 0.f, 0.f, 0.f};
                if (c < C) {
                    vw = *(const float4*)&wpt[(size_t)c * M2 + m0 + col];
                    vx = *(const float4*)&xb[(size_t)c * N_PTS + n0 + col];
                }
                *(float4*)&sU0[r][col] = vw;
                *(float4*)&sU1[r][col] = vx;
            }
            __syncthreads();
            for (int k = 0; k < 16; k++) {
                float4 a0 = *(const float4*)&sU0[k][ty * 4];
                float4 a1 = *(const float4*)&sU0[k][64 + ty * 4];
                float4 b0 = *(const float4*)&sU1[k][tx * 4];
                float4 b1 = *(const float4*)&sU1[k][64 + tx * 4];
                float av[8] = {a0.x, a0.y, a0.z, a0.w, a1.x, a1.y, a1.z, a1.w};
                float bw[8] = {b0.x, b0.y, b0.z, b0.w, b1.x, b1.y, b1.z, b1.w};
                for (int i = 0; i < 8; i++)
                    for (int j = 0; j < 8; j++) acc[i][j] += av[i] * bw[j];
            }
            __syncthreads();
        }
        for (int i = 0; i < 8; i++) {
            int rowm = m0 + (i >> 2) * 64 + ty * 4 + (i & 3);
            float* dst = (rowm < Cout) ? (A + ((size_t)b * Cout + rowm) * N_PTS)
                                       : (Bv + ((size_t)b * Cout + rowm - Cout) * N_PTS);
            for (int jh = 0; jh < 2; jh++) {
                float4 o;
                o.x = acc[i][jh * 4 + 0];
                o.y = acc[i][jh * 4 + 1];
                o.z = acc[i][jh * 4 + 2];
                o.w = acc[i][jh * 4 + 3];
                *(float4*)&dst[n0 + jh * 64 + tx * 4] = o;
            }
        }
    }
}

// ---------------- top-20 per row: threshold-compact + bitonic select ----------------
__global__ void __launch_bounds__(256)
topk_kernel(const float* __restrict__ pd, int* __restrict__ idx) {
    int wid = threadIdx.x >> 6;
    int row = blockIdx.x * 4 + wid;          // row = b*N + n
    int lane = threadIdx.x & 63;
    __shared__ u64 Sk[4][64];
    const float* p = pd + (size_t)row * N_PTS;
    float v[16];
    for (int q = 0; q < 4; q++) {
        float4 t = *(const float4*)&p[lane * 16 + q * 4];
        v[q * 4 + 0] = t.x; v[q * 4 + 1] = t.y; v[q * 4 + 2] = t.z; v[q * 4 + 3] = t.w;
    }
    float lmax = v[0];
    #pragma unroll
    for (int j = 1; j < 16; j++) lmax = fmaxf(lmax, v[j]);
    float s = lmax;
    #pragma unroll
    for (int k = 2; k <= 64; k <<= 1) {
        #pragma unroll
        for (int j = k >> 1; j > 0; j >>= 1) {
            float o = __shfl_xor(s, j, 64);
            bool takeMin = (((lane & k) == 0) == ((lane & j) == 0));
            float mn = fminf(s, o), mx = fmaxf(s, o);
            s = takeMin ? mn : mx;
        }
    }
    float tp = __shfl(s, 44, 64);            // 20th largest lane-max
    unsigned hm = 0;
    #pragma unroll
    for (int j = 0; j < 16; j++) hm |= (v[j] >= tp ? 1u : 0u) << j;
    int cnt = __popc(hm);
    int incl = cnt;
    #pragma unroll
    for (int d = 1; d < 64; d <<= 1) {
        int o = __shfl_up(incl, d, 64);
        if (lane >= d) incl += o;
    }
    int total = __shfl(incl, 63, 64);
    int pos = incl - cnt;
    if (total <= 64) {
        #pragma unroll
        for (int j = 0; j < 16; j++) {
            if (hm & (1u << j)) {
                unsigned u = __float_as_uint(v[j]);
                unsigned msk = ((unsigned)((int)u >> 31)) | 0x80000000u;
                Sk[wid][pos] = ((u64)(u ^ msk) << 32) | (unsigned)(1023 - (lane * 16 + j));
                pos++;
            }
        }
        u64 key = (lane < total) ? Sk[wid][lane] : 0ull;
        #pragma unroll
        for (int k = 2; k <= 64; k <<= 1) {
            #pragma unroll
            for (int j = k >> 1; j > 0; j >>= 1) {
                u64 o = __shfl_xor(key, j, 64);
                bool takeMin = (((lane & k) == 0) == ((lane & j) == 0));
                bool sgt = key > o;
                key = (sgt != takeMin) ? key : o;
            }
        }
        if (lane >= 44) {
            int m = 1023 - (int)(unsigned)(key & 0xFFFFFFFFu);
            idx[row * KNN + (63 - lane)] = m;
        }
    } else {
        for (int kk = 0; kk < KNN; kk++) {
            float bv = v[0]; int bj = 0;
            #pragma unroll
            for (int j = 1; j < 16; j++) if (v[j] > bv) { bv = v[j]; bj = j; }
            int bi = lane * 16 + bj;
            for (int d = 32; d > 0; d >>= 1) {
                float ov = __shfl_down(bv, d, 64);
                int oi = __shfl_down(bi, d, 64);
                if (ov > bv || (ov == bv && oi < bi)) { bv = ov; bi = oi; }
            }
            bi = __shfl(bi, 0, 64);
            if ((bi >> 4) == lane) {
                #pragma unroll
                for (int j = 0; j < 16; j++) if (j == (bi & 15)) v[j] = -INFINITY;
            }
            if (lane == 0) idx[row * KNN + kk] = bi;
        }
    }
}

// ---------------- gmax: LDS-staged gather-max + BN + lrelu ----------------
__global__ void __launch_bounds__(256)
gmax_kernel(const float* __restrict__ A, const float* __restrict__ Bv,
            const int* __restrict__ idx, const float* __restrict__ bnp,
            float* __restrict__ out, int Cout, int outStrideB) {
    int b = blockIdx.z;
    int n0 = blockIdx.x * 64;
    int o0 = blockIdx.y * 4;
    int tid = threadIdx.x;
    __shared__ int sidx[64 * 21];
    __shared__ float sA[4][N_PTS];
    for (int t = tid; t < 64 * KNN; t += 256) {
        int nl = t / KNN, k = t - nl * KNN;
        sidx[nl * 21 + k] = idx[(b * N_PTS + n0) * KNN + t];
    }
    const float* Abase = A + ((size_t)b * Cout + o0) * N_PTS;
    for (int q = 0; q < 4; q++) {
        int f = q * 256 + tid;
        int r = f >> 8, c4 = (f & 255) * 4;
        *(float4*)&sA[r][c4] = *(const float4*)&Abase[(size_t)r * N_PTS + c4];
    }
    __syncthreads();
    int nl = tid & 63, ol = tid >> 6;
    float best = -INFINITY;
    #pragma unroll
    for (int k = 0; k < KNN; k++) {
        int j = sidx[nl * 21 + k];
        best = fmaxf(best, sA[ol][j]);
    }
    int o = o0 + ol;
    int n = n0 + nl;
    float pre = best + Bv[((size_t)b * Cout + o) * N_PTS + n];
    float g = bnp[o], bb = bnp[Cout + o], m = bnp[2 * Cout + o], vv = bnp[3 * Cout + o];
    float scale = g / sqrtf(vv + EPSB);
    out[(size_t)b * outStrideB + (size_t)o * N_PTS + n] = lrelu((pre - m) * scale + bb);
}

// ---------------- cat fp32 [b][c][n] -> catT bf16 [b][n][c] ----------------
__global__ void catT_kernel(const float* __restrict__ cat, ushort_t* __restrict__ catT) {
    int b = blockIdx.z, ct = blockIdx.y, nt = blockIdx.x;
    int tid = threadIdx.x;
    __shared__ float tile[64][65];
    const float* cb = cat + (size_t)b * 512 * N_PTS;
    for (int q = 0; q < 16; q++) {
        int e = q * 256 + tid;
        int c = e >> 6, n = e & 63;
        tile[c][n] = cb[(size_t)(ct * 64 + c) * N_PTS + nt * 64 + n];
    }
    __syncthreads();
    for (int q = 0; q < 16; q++) {
        int e = q * 256 + tid;
        int n = e >> 6, c = e & 63;
        catT[((size_t)b * N_PTS + nt * 64 + n) * 512 + ct * 64 + c] = f2bf(tile[c][n]);
    }
}

// ---------------- embedding GEMM (bf16 MFMA) + bn + lrelu + fused max/sum ----------------
__global__ void __launch_bounds__(256)
gemm6_mfma(const ushort_t* __restrict__ weh, const ushort_t* __restrict__ catT,
           const float* __restrict__ bne,
           float* __restrict__ pmax, float* __restrict__ psum) {
    int b = blockIdx.z, ot = blockIdx.y, nt = blockIdx.x;
    int tid = threadIdx.x;
    int w = tid >> 6, lane = tid & 63, q = lane >> 4, lr = lane & 15;
    int mblk = w >> 1, nblk = w & 1;
    __shared__ __align__(16) ushort_t sA[128 * 40];
    __shared__ __align__(16) ushort_t sB[128 * 40];
    __shared__ float sa[128], sc[128];
    __shared__ float redmax[128][2], redsum[128][2];
    int o0 = ot * 128, n0 = nt * 128;
    if (tid < 128) {
        int o = o0 + tid;
        float g = bne[o], bb = bne[1024 + o], m = bne[2048 + o], vv = bne[3072 + o];
        float scale = g / sqrtf(vv + EPSB);
        sa[tid] = scale; sc[tid] = bb - m * scale;
    }
    f32x4 acc[4][4] = {};
    const ushort_t* cT = catT + (size_t)b * N_PTS * 512;
    int r0 = tid >> 2, s = tid & 3;
    for (int k0 = 0; k0 < 512; k0 += 32) {
        __syncthreads();
        for (int h = 0; h < 2; h++) {
            int r = r0 + h * 64;
            *(short8*)&sA[r * 40 + s * 8] = *(const short8*)(weh + (size_t)(o0 + r) * 512 + k0 + s * 8);
            *(short8*)&sB[r * 40 + s * 8] = *(const short8*)(cT  + (size_t)(n0 + r) * 512 + k0 + s * 8);
        }
        __syncthreads();
        short8 af[4], bfr[4];
        for (int mi = 0; mi < 4; mi++)
            af[mi] = *(const short8*)&sA[(mblk * 64 + mi * 16 + lr) * 40 + q * 8];
        for (int ni = 0; ni < 4; ni++)
            bfr[ni] = *(const short8*)&sB[(nblk * 64 + ni * 16 + lr) * 40 + q * 8];
        for (int mi = 0; mi < 4; mi++)
            for (int ni = 0; ni < 4; ni++)
                acc[mi][ni] = __builtin_amdgcn_mfma_f32_16x16x32_bf16(af[mi], bfr[ni], acc[mi][ni], 0, 0, 0);
    }
    for (int mi = 0; mi < 4; mi++) {
        for (int r = 0; r < 4; r++) {
            int row = mblk * 64 + mi * 16 + q * 4 + r;
            float a = sa[row], c = sc[row];
            float mx = -INFINITY, sm = 0.f;
            for (int ni = 0; ni < 4; ni++) {
                float y = lrelu(acc[mi][ni][r] * a + c);
                mx = fmaxf(mx, y); sm += y;
            }
            for (int msk = 1; msk < 16; msk <<= 1) {
                mx = fmaxf(mx, __shfl_xor(mx, msk, 16));
                sm += __shfl_xor(sm, msk, 16);
            }
            if (lr == 0) { redmax[row][nblk] = mx; redsum[row][nblk] = sm; }
        }
    }
    __syncthreads();
    if (tid < 128) {
        float mx = fmaxf(redmax[tid][0], redmax[tid][1]);
        float sm = redsum[tid][0] + redsum[tid][1];
        int o = o0 + tid;
        pmax[((size_t)(b * 1024 + o)) * 8 + nt] = mx;
        psum[((size_t)(b * 1024 + o)) * 8 + nt] = sm;
    }
}

__global__ void pool_reduce_kernel(const float* __restrict__ pmax, const float* __restrict__ psum,
                                   float* __restrict__ h0) {
    int g = blockIdx.x * 256 + threadIdx.x;  // b*1024 + o
    int b = g >> 10, o = g & 1023;
    float mx = -INFINITY, sm = 0.f;
    for (int t = 0; t < 8; t++) { mx = fmaxf(mx, pmax[g * 8 + t]); sm += psum[g * 8 + t]; }
    h0[(size_t)b * 2048 + o] = mx;
    h0[(size_t)b * 2048 + 1024 + o] = sm * (1.0f / 1024.0f);
}

// ---------------- FC: one wave per output ----------------
__global__ void fc_kernel(const float* __restrict__ in, const float* __restrict__ w,
                          const float* __restrict__ bnp, const float* __restrict__ bias,
                          float* __restrict__ out, int Cin, int Cout, int mode) {
    int blk = blockIdx.x;  // b*Cout + o
    int b = blk / Cout, o = blk % Cout;
    int lane = threadIdx.x;
    const float* inb = in + (size_t)b * Cin;
    const float* wo = w + (size_t)o * Cin;
    float acc = 0.f;
    for (int c = lane; c < Cin; c += 64) acc += inb[c] * wo[c];
    for (int s = 32; s > 0; s >>= 1) acc += __shfl_down(acc, s, 64);
    if (lane == 0) {
        float y = acc;
        if (mode == 0) {
            float g = bnp[o], bb = bnp[Cout + o], m = bnp[2 * Cout + o], vv = bnp[3 * Cout + o];
            y = lrelu((y - m) * (g / sqrtf(vv + EPSB)) + bb);
        } else {
            y += bias[o];
        }
        out[(size_t)b * Cout + o] = y;
    }
}

extern "C" void kernel_launch(void* const* d_in, const int* in_sizes, int n_in,
                              void* d_out, int out_size, void* d_ws, size_t ws_size,
                              hipStream_t stream) {
    const float* x    = (const float*)d_in[0];
    const float* w0   = (const float*)d_in[1];
    const float* w1   = (const float*)d_in[2];
    const float* w2   = (const float*)d_in[3];
    const float* w3   = (const float*)d_in[4];
    const float* bn0  = (const float*)d_in[5];
    const float* bn1  = (const float*)d_in[6];
    const float* bn2  = (const float*)d_in[7];
    const float* bn3  = (const float*)d_in[8];
    const float* we   = (const float*)d_in[9];
    const float* bne  = (const float*)d_in[10];
    const float* wf0  = (const float*)d_in[11];
    const float* bnf0 = (const float*)d_in[12];
    const float* wf1  = (const float*)d_in[13];
    const float* bnf1 = (const float*)d_in[14];
    const float* wfin = (const float*)d_in[15];
    const float* bfin = (const float*)d_in[16];

    float* ws = (float*)d_ws;
    size_t off = 0;
    float* cat  = ws + off; off += (size_t)BATCH * 512 * N_PTS;        // 16 MB
    float* pd   = ws + off; off += (size_t)BATCH * N_PTS * N_PTS;      // 33.5 MB
    float* A    = ws + off; off += (size_t)BATCH * 256 * N_PTS;        // 8 MB (disjoint from pd)
    float* Bv   = ws + off; off += (size_t)BATCH * 256 * N_PTS;        // 8 MB
    float* pmax = ws + off; off += (size_t)BATCH * N_PTS * 8;
    float* psum = ws + off; off += (size_t)BATCH * N_PTS * 8;
    float* h0   = ws + off; off += (size_t)BATCH * 2048;
    float* h1   = ws + off; off += (size_t)BATCH * 512;
    float* h2   = ws + off; off += (size_t)BATCH * 256;
    float* xxv  = ws + off; off += (size_t)BATCH * N_PTS;
    int*   idx  = (int*)(ws + off); off += (size_t)BATCH * N_PTS * KNN;
    ushort_t* weh  = (ushort_t*)(ws + off); off += (size_t)(1024 * 512) / 2;        // 1 MB
    ushort_t* catT = (ushort_t*)(ws + off); off += (size_t)BATCH * N_PTS * 512 / 2; // 8 MB
    ushort_t* xT3  = (ushort_t*)(ws + off); off += (size_t)BATCH * N_PTS * 3 * 128 / 2; // 6.3 MB (max C=128)
    ushort_t* Wext1 = (ushort_t*)(ws + off); off += (size_t)(128 * 3 * 64) / 2;
    ushort_t* Wext2 = (ushort_t*)(ws + off); off += (size_t)(256 * 3 * 64) / 2;
    ushort_t* Wext3 = (ushort_t*)(ws + off); off += (size_t)(512 * 3 * 128) / 2;
    float* wpt0 = ws + off; off += 3 * 128;

    const int CSTR = 512 * N_PTS;   // cat batch stride
    const int topkBlocks = BATCH * N_PTS / 4;

    // ---- all weight prep in one launch
    prep_kernel<<<866, 256, 0, stream>>>(we, weh, w0, wpt0, w1, Wext1, w2, Wext2, w3, Wext3);

    // ---- block 0: input x (B,3,N), C=3 -> Cout=64, out ch [0,64)  (VALU path)
    pdabv_valu<<<dim3(9, 8, BATCH), 256, 0, stream>>>(x, wpt0, pd, A, Bv, 3, 64, 3 * N_PTS);
    topk_kernel<<<topkBlocks, 256, 0, stream>>>(pd, idx);
    gmax_kernel<<<dim3(16, 16, BATCH), 256, 0, stream>>>(A, Bv, idx, bn0, cat, 64, CSTR);

    // ---- block 1: C=64 -> Cout=64, out ch [64,128)  (MFMA bf16x3)
    split_kernel<<<dim3(16, 1, BATCH), 256, 0, stream>>>(cat, xT3, xxv, 64, CSTR);
    pdabv_mfma<<<dim3(8, 9, BATCH), 256, 0, stream>>>(xT3, Wext1, xxv, pd, A, Bv, 64, 6, 64);
    topk_kernel<<<topkBlocks, 256, 0, stream>>>(pd, idx);
    gmax_kernel<<<dim3(16, 16, BATCH), 256, 0, stream>>>(A, Bv, idx, bn1, cat + 64 * N_PTS, 64, CSTR);

    // ---- block 2: C=64 -> Cout=128, out ch [128,256)
    split_kernel<<<dim3(16, 1, BATCH), 256, 0, stream>>>(cat + 64 * N_PTS, xT3, xxv, 64, CSTR);
    pdabv_mfma<<<dim3(8, 10, BATCH), 256, 0, stream>>>(xT3, Wext2, xxv, pd, A, Bv, 64, 6, 128);
    topk_kernel<<<topkBlocks, 256, 0, stream>>>(pd, idx);
    gmax_kernel<<<dim3(16, 32, BATCH), 256, 0, stream>>>(A, Bv, idx, bn2, cat + 128 * N_PTS, 128, CSTR);

    // ---- block 3: C=128 -> Cout=256, out ch [256,512)
    split_kernel<<<dim3(16, 1, BATCH), 256, 0, stream>>>(cat + 128 * N_PTS, xT3, xxv, 128, CSTR);
    pdabv_mfma<<<dim3(8, 12, BATCH), 256, 0, stream>>>(xT3, Wext3, xxv, pd, A, Bv, 128, 7, 256);
    topk_kernel<<<topkBlocks, 256, 0, stream>>>(pd, idx);
    gmax_kernel<<<dim3(16, 64, BATCH), 256, 0, stream>>>(A, Bv, idx, bn3, cat + 256 * N_PTS, 256, CSTR);

    // ---- cat -> bf16 transposed, then MFMA embedding + pooling
    catT_kernel<<<dim3(16, 8, BATCH), 256, 0, stream>>>(cat, catT);
    gemm6_mfma<<<dim3(8, 8, BATCH), 256, 0, stream>>>(weh, catT, bne, pmax, psum);
    pool_reduce_kernel<<<32, 256, 0, stream>>>(pmax, psum, h0);

    // ---- FC head
    fc_kernel<<<BATCH * 512, 64, 0, stream>>>(h0, wf0, bnf0, nullptr, h1, 2048, 512, 0);
    fc_kernel<<<BATCH * 256, 64, 0, stream>>>(h1, wf1, bnf1, nullptr, h2, 512, 256, 0);
    fc_kernel<<<BATCH * 64, 64, 0, stream>>>(h2, wfin, nullptr, bfin, (float*)d_out, 256, 64, 1);
}

// Round 9
// 338.823 us; speedup vs baseline: 1.0128x; 1.0128x over previous
//
#include <hip/hip_runtime.h>
#include <math.h>

#define N_PTS 1024
#define BATCH 8
#define KNN 20
#define EPSB 1e-5f
#define SLOPE 0.2f

typedef __attribute__((ext_vector_type(8))) short short8;
typedef __attribute__((ext_vector_type(4))) float f32x4;
typedef unsigned short ushort_t;
typedef unsigned long long u64;

#define LDS_U32(p) ((__attribute__((address_space(3))) unsigned int*)(p))
#define GLB_U32(p) ((const __attribute__((address_space(1))) unsigned int*)(p))

// async global->LDS, 16B/lane; lds base must be wave-uniform (lane i lands at base + i*16B)
__device__ __forceinline__ void glds16(const ushort_t* g, ushort_t* l) {
    __builtin_amdgcn_global_load_lds(GLB_U32(g), LDS_U32(l), 16, 0, 0);
}

__device__ __forceinline__ float lrelu(float y) { return y > 0.f ? y : SLOPE * y; }

__device__ __forceinline__ ushort_t f2bf(float f) {
    union { float f; unsigned u; } v; v.f = f;
    unsigned r = v.u + 0x7FFF + ((v.u >> 16) & 1);   // RNE
    return (ushort_t)(r >> 16);
}
__device__ __forceinline__ float bf2f(ushort_t h) {
    union { unsigned u; float f; } v; v.u = ((unsigned)h) << 16; return v.f;
}

// ---------------- weight prep ----------------
__device__ __forceinline__ void wprep_one(const float* __restrict__ w, float* __restrict__ wpt,
                                          int C, int Cout, int g) {
    int M2 = 2 * Cout;
    if (g >= C * M2) return;
    int c = g / M2, m = g - c * M2;
    float v;
    if (m < Cout) v = w[(size_t)m * 2 * C + c];
    else { int o = m - Cout; v = w[(size_t)o * 2 * C + C + c] - w[(size_t)o * 2 * C + c]; }
    wpt[(size_t)c * M2 + m] = v;
}

// W' -> bf16x3 planes, layout [m][3C] (h at +0, mid at +C, lo at +2C)
__device__ __forceinline__ void wext_one(const float* __restrict__ w, ushort_t* __restrict__ Wext,
                                         int C, int Cout, int g, int lg2C) {
    int M2 = 2 * Cout;
    if (g >= C * M2) return;
    int m = g >> lg2C, c = g & (C - 1);
    float v;
    if (m < Cout) v = w[(size_t)m * 2 * C + c];
    else { int o = m - Cout; v = w[(size_t)o * 2 * C + C + c] - w[(size_t)o * 2 * C + c]; }
    ushort_t h = f2bf(v);
    float r1 = v - bf2f(h);
    ushort_t md = f2bf(r1);
    ushort_t lo = f2bf(r1 - bf2f(md));
    ushort_t* dst = Wext + (size_t)m * 3 * C + c;
    dst[0] = h; dst[C] = md; dst[2 * C] = lo;
}

__global__ void prep_kernel(const float* __restrict__ we, ushort_t* __restrict__ weh,
                            const float* __restrict__ w0, float* __restrict__ wpt0,
                            const float* __restrict__ w1, ushort_t* __restrict__ Wext1,
                            const float* __restrict__ w2, ushort_t* __restrict__ Wext2,
                            const float* __restrict__ w3, ushort_t* __restrict__ Wext3) {
    int bx = blockIdx.x, tid = threadIdx.x;
    if (bx < 512) {
        int g = bx * 256 + tid;
        float4 v = ((const float4*)we)[g];
        ushort4 o;
        o.x = f2bf(v.x); o.y = f2bf(v.y); o.z = f2bf(v.z); o.w = f2bf(v.w);
        ((ushort4*)weh)[g] = o;
    } else if (bx < 514) {
        wprep_one(w0, wpt0, 3, 64, (bx - 512) * 256 + tid);
    } else if (bx < 546) {
        wext_one(w1, Wext1, 64, 64, (bx - 514) * 256 + tid, 6);
    } else if (bx < 610) {
        wext_one(w2, Wext2, 64, 128, (bx - 546) * 256 + tid, 6);
    } else {
        wext_one(w3, Wext3, 128, 256, (bx - 610) * 256 + tid, 7);
    }
}

// ---------------- split: fp32 [C][N] slice -> xT3 bf16 [n][3C] planes + exact fp32 xx ----------------
__global__ void __launch_bounds__(256)
split_kernel(const float* __restrict__ in, ushort_t* __restrict__ xT3,
             float* __restrict__ xxv, int C, int bstride) {
    int b = blockIdx.z, nt = blockIdx.x;
    int tid = threadIdx.x;
    __shared__ float tile[64][65];
    const float* ib = in + (size_t)b * bstride;
    int S3 = 3 * C;
    float xxa = 0.f;
    for (int ct = 0; ct < C; ct += 64) {
        __syncthreads();
        for (int qq = 0; qq < 16; qq++) {
            int e = qq * 256 + tid;
            int c = e >> 6, n = e & 63;
            tile[c][n] = ib[(size_t)(ct + c) * N_PTS + nt * 64 + n];
        }
        __syncthreads();
        if (tid < 64) {
            for (int c = 0; c < 64; c++) { float v = tile[c][tid]; xxa += v * v; }
        }
        for (int qq = 0; qq < 16; qq++) {
            int e = qq * 256 + tid;
            int n = e >> 6, c = e & 63;
            float v = tile[c][n];
            ushort_t h = f2bf(v);
            float r1 = v - bf2f(h);
            ushort_t md = f2bf(r1);
            ushort_t lo = f2bf(r1 - bf2f(md));
            ushort_t* dst = xT3 + ((size_t)b * N_PTS + nt * 64 + n) * S3 + ct + c;
            dst[0] = h; dst[C] = md; dst[2 * C] = lo;
        }
    }
    if (tid < 64) xxv[b * N_PTS + nt * 64 + tid] = xxa;
}

// ---------------- MFMA pd+abv: bf16x3 K-expansion, glds staging ----------------
// mt < 8 : pd tile (6 segments, fp32-parity)   pd = 2*dot - xx[n] - xx[m]
// mt >= 8: abv tile (3 segments, ~2^-16 rel)   W' -> A / Bv
// LDS tiles [128][32] shorts UNPADDED (64B rows) — required by global_load_lds mapping.
__global__ void __launch_bounds__(256)
pdabv_mfma(const ushort_t* __restrict__ xT3, const ushort_t* __restrict__ Wext,
           const float* __restrict__ xxv,
           float* __restrict__ pd, float* __restrict__ A, float* __restrict__ Bv,
           int C, int lg2C, int Cout) {
    int b = blockIdx.z, mt = blockIdx.y, nt = blockIdx.x;
    int tid = threadIdx.x;
    int wv = tid >> 6, lane = tid & 63, q = lane >> 4, lr = lane & 15;
    int mblk = wv >> 1, nblk = wv & 1;
    int srow = lane >> 2;            // 0..15  (glds row within 16-row chunk)
    int scol = (lane & 3) * 8;       // shorts (16B column)
    const int S3 = 3 * C;
    bool isPd = (mt < 8);
    const ushort_t* Abase = isPd ? (xT3 + ((size_t)b * N_PTS + mt * 128) * S3)
                                 : (Wext + (size_t)(mt - 8) * 128 * S3);
    const ushort_t* Bbase = xT3 + ((size_t)b * N_PTS + nt * 128) * S3;
    __shared__ __align__(16) ushort_t sA[128 * 32];
    __shared__ __align__(16) ushort_t sB[128 * 32];
    __shared__ float sxxA[128], sxxB[128];
    if (isPd && tid < 128) {
        sxxA[tid] = xxv[b * N_PTS + mt * 128 + tid];
        sxxB[tid] = xxv[b * N_PTS + nt * 128 + tid];
    }
    f32x4 acc[4][4] = {};
    const int pA6[6] = {0, 0, 1, 1, 0, 2};   // pd planes: hh,hm,mh,mm,hl,lh
    const int pB6[6] = {0, 1, 0, 1, 2, 0};
    const int pA3[3] = {0, 0, 1};            // abv planes: hh,hm,mh
    const int pB3[3] = {0, 1, 0};
    int nseg = isPd ? 6 : 3;
    for (int ks = 0; ks < nseg * C; ks += 32) {
        int seg = ks >> lg2C;
        int kl = ks & (C - 1);
        int aoff = (isPd ? pA6[seg] : pA3[seg]) * C + kl;
        int boff = (isPd ? pB6[seg] : pB3[seg]) * C + kl;
        __syncthreads();
        #pragma unroll
        for (int h = 0; h < 2; h++) {
            int chunk = wv + h * 4;          // wave-uniform
            int row = chunk * 16 + srow;
            glds16(Abase + (size_t)row * S3 + aoff + scol, sA + chunk * 512);
            glds16(Bbase + (size_t)row * S3 + boff + scol, sB + chunk * 512);
        }
        __syncthreads();
        short8 af[4], bfr[4];
        for (int mi = 0; mi < 4; mi++)
            af[mi] = *(const short8*)&sA[(mblk * 64 + mi * 16 + lr) * 32 + q * 8];
        for (int ni = 0; ni < 4; ni++)
            bfr[ni] = *(const short8*)&sB[(nblk * 64 + ni * 16 + lr) * 32 + q * 8];
        for (int mi = 0; mi < 4; mi++)
            for (int ni = 0; ni < 4; ni++)
                acc[mi][ni] = __builtin_amdgcn_mfma_f32_16x16x32_bf16(af[mi], bfr[ni], acc[mi][ni], 0, 0, 0);
    }
    if (isPd) {
        for (int mi = 0; mi < 4; mi++)
        for (int r = 0; r < 4; r++) {
            int row = mblk * 64 + mi * 16 + q * 4 + r;
            float xr = sxxA[row];
            float* prow = pd + ((size_t)(b * N_PTS + mt * 128 + row)) * N_PTS + nt * 128;
            for (int ni = 0; ni < 4; ni++) {
                int col = nblk * 64 + ni * 16 + lr;
                prow[col] = 2.f * acc[mi][ni][r] - xr - sxxB[col];
            }
        }
    } else {
        for (int mi = 0; mi < 4; mi++)
        for (int r = 0; r < 4; r++) {
            int rowm = (mt - 8) * 128 + mblk * 64 + mi * 16 + q * 4 + r;
            float* dst = (rowm < Cout) ? (A + ((size_t)b * Cout + rowm) * N_PTS)
                                       : (Bv + ((size_t)b * Cout + rowm - Cout) * N_PTS);
            for (int ni = 0; ni < 4; ni++) {
                int col = nblk * 64 + ni * 16 + lr;
                dst[nt * 128 + col] = acc[mi][ni][r];
            }
        }
    }
}

// ---------------- layer-0 fused pd + abv (VALU fp32, C=3) ----------------
__global__ void __launch_bounds__(256)
pdabv_valu(const float* __restrict__ x, const float* __restrict__ wpt,
           float* __restrict__ pd, float* __restrict__ A, float* __restrict__ Bv,
           int C, int Cout, int bstride) {
    int b = blockIdx.z;
    int nt = blockIdx.y;
    int bx = blockIdx.x;
    int tid = threadIdx.x;
    int tx = tid & 15, ty = tid >> 4;
    int n0 = nt * 128;
    __shared__ float sU0[16][128];
    __shared__ float sU1[16][128];
    __shared__ float sXX[256];
    const float* xb = x + (size_t)b * bstride;
    float acc[8][8] = {};
    if (bx < 8) {
        int m0 = bx * 128;
        float xxa = 0.f;
        for (int c0 = 0; c0 < C; c0 += 16) {
            for (int q = 0; q < 2; q++) {
                int f = q * 256 + tid;
                int r = f >> 5, col = (f & 31) * 4;
                int c = c0 + r;
                float4 vn = {0.f, 0.f, 0.f, 0.f}, vm = {0.f, 0.f, 0.f, 0.f};
                if (c < C) {
                    vn = *(const float4*)&xb[(size_t)c * N_PTS + n0 + col];
                    vm = *(const float4*)&xb[(size_t)c * N_PTS + m0 + col];
                }
                *(float4*)&sU0[r][col] = vn;
                *(float4*)&sU1[r][col] = vm;
            }
            __syncthreads();
            if (tid < 128) {
                for (int k = 0; k < 16; k++) { float v = sU0[k][tid]; xxa += v * v; }
            } else {
                int u = tid - 128;
                for (int k = 0; k < 16; k++) { float v = sU1[k][u]; xxa += v * v; }
            }
            for (int k = 0; k < 16; k++) {
                float4 a0 = *(const float4*)&sU0[k][ty * 4];
                float4 a1 = *(const float4*)&sU0[k][64 + ty * 4];
                float4 b0 = *(const float4*)&sU1[k][tx * 4];
                float4 b1 = *(const float4*)&sU1[k][64 + tx * 4];
                float av[8] = {a0.x, a0.y, a0.z, a0.w, a1.x, a1.y, a1.z, a1.w};
                float bw[8] = {b0.x, b0.y, b0.z, b0.w, b1.x, b1.y, b1.z, b1.w};
                for (int i = 0; i < 8; i++)
                    for (int j = 0; j < 8; j++) acc[i][j] += av[i] * bw[j];
            }
            __syncthreads();
        }
        sXX[tid] = xxa;
        __syncthreads();
        float xnv[8], xmv[8];
        for (int i = 0; i < 8; i++) xnv[i] = sXX[(i >> 2) * 64 + ty * 4 + (i & 3)];
        for (int j = 0; j < 8; j++) xmv[j] = sXX[128 + (j >> 2) * 64 + tx * 4 + (j & 3)];
        for (int i = 0; i < 8; i++) {
            int n = n0 + (i >> 2) * 64 + ty * 4 + (i & 3);
            float* prow = pd + ((size_t)(b * N_PTS + n)) * N_PTS;
            for (int jh = 0; jh < 2; jh++) {
                float4 o;
                o.x = 2.f * acc[i][jh * 4 + 0] - xnv[i] - xmv[jh * 4 + 0];
                o.y = 2.f * acc[i][jh * 4 + 1] - xnv[i] - xmv[jh * 4 + 1];
                o.z = 2.f * acc[i][jh * 4 + 2] - xnv[i] - xmv[jh * 4 + 2];
                o.w = 2.f * acc[i][jh * 4 + 3] - xnv[i] - xmv[jh * 4 + 3];
                *(float4*)&prow[m0 + jh * 64 + tx * 4] = o;
            }
        }
    } else {
        int m0 = (bx - 8) * 128;
        int M2 = 2 * Cout;
        for (int c0 = 0; c0 < C; c0 += 16) {
            for (int q = 0; q < 2; q++) {
                int f = q * 256 + tid;
                int r = f >> 5, col = (f & 31) * 4;
                int c = c0 + r;
                float4 vw = {0.f, 0.f, 0.f, 0.f}, vx = {0.f, 0.f, 0.f, 0.f};
                if (c < C) {
                    vw = *(const float4*)&wpt[(size_t)c * M2 + m0 + col];
                    vx = *(const float4*)&xb[(size_t)c * N_PTS + n0 + col];
                }
                *(float4*)&sU0[r][col] = vw;
                *(float4*)&sU1[r][col] = vx;
            }
            __syncthreads();
            for (int k = 0; k < 16; k++) {
                float4 a0 = *(const float4*)&sU0[k][ty * 4];
                float4 a1 = *(const float4*)&sU0[k][64 + ty * 4];
                float4 b0 = *(const float4*)&sU1[k][tx * 4];
                float4 b1 = *(const float4*)&sU1[k][64 + tx * 4];
                float av[8] = {a0.x, a0.y, a0.z, a0.w, a1.x, a1.y, a1.z, a1.w};
                float bw[8] = {b0.x, b0.y, b0.z, b0.w, b1.x, b1.y, b1.z, b1.w};
                for (int i = 0; i < 8; i++)
                    for (int j = 0; j < 8; j++) acc[i][j] += av[i] * bw[j];
            }
            __syncthreads();
        }
        for (int i = 0; i < 8; i++) {
            int rowm = m0 + (i >> 2) * 64 + ty * 4 + (i & 3);
            float* dst = (rowm < Cout) ? (A + ((size_t)b * Cout + rowm) * N_PTS)
                                       : (Bv + ((size_t)b * Cout + rowm - Cout) * N_PTS);
            for (int jh = 0; jh < 2; jh++) {
                float4 o;
                o.x = acc[i][jh * 4 + 0];
                o.y = acc[i][jh * 4 + 1];
                o.z = acc[i][jh * 4 + 2];
                o.w = acc[i][jh * 4 + 3];
                *(float4*)&dst[n0 + jh * 64 + tx * 4] = o;
            }
        }
    }
}

// ---------------- top-20 per row: threshold-compact + bitonic select ----------------
__global__ void __launch_bounds__(256)
topk_kernel(const float* __restrict__ pd, int* __restrict__ idx) {
    int wid = threadIdx.x >> 6;
    int row = blockIdx.x * 4 + wid;          // row = b*N + n
    int lane = threadIdx.x & 63;
    __shared__ u64 Sk[4][64];
    const float* p = pd + (size_t)row * N_PTS;
    float v[16];
    for (int q = 0; q < 4; q++) {
        float4 t = *(const float4*)&p[lane * 16 + q * 4];
        v[q * 4 + 0] = t.x; v[q * 4 + 1] = t.y; v[q * 4 + 2] = t.z; v[q * 4 + 3] = t.w;
    }
    float lmax = v[0];
    #pragma unroll
    for (int j = 1; j < 16; j++) lmax = fmaxf(lmax, v[j]);
    float s = lmax;
    #pragma unroll
    for (int k = 2; k <= 64; k <<= 1) {
        #pragma unroll
        for (int j = k >> 1; j > 0; j >>= 1) {
            float o = __shfl_xor(s, j, 64);
            bool takeMin = (((lane & k) == 0) == ((lane & j) == 0));
            float mn = fminf(s, o), mx = fmaxf(s, o);
            s = takeMin ? mn : mx;
        }
    }
    float tp = __shfl(s, 44, 64);            // 20th largest lane-max
    unsigned hm = 0;
    #pragma unroll
    for (int j = 0; j < 16; j++) hm |= (v[j] >= tp ? 1u : 0u) << j;
    int cnt = __popc(hm);
    int incl = cnt;
    #pragma unroll
    for (int d = 1; d < 64; d <<= 1) {
        int o = __shfl_up(incl, d, 64);
        if (lane >= d) incl += o;
    }
    int total = __shfl(incl, 63, 64);
    int pos = incl - cnt;
    if (total <= 64) {
        #pragma unroll
        for (int j = 0; j < 16; j++) {
            if (hm & (1u << j)) {
                unsigned u = __float_as_uint(v[j]);
                unsigned msk = ((unsigned)((int)u >> 31)) | 0x80000000u;
                Sk[wid][pos] = ((u64)(u ^ msk) << 32) | (unsigned)(1023 - (lane * 16 + j));
                pos++;
            }
        }
        u64 key = (lane < total) ? Sk[wid][lane] : 0ull;
        #pragma unroll
        for (int k = 2; k <= 64; k <<= 1) {
            #pragma unroll
            for (int j = k >> 1; j > 0; j >>= 1) {
                u64 o = __shfl_xor(key, j, 64);
                bool takeMin = (((lane & k) == 0) == ((lane & j) == 0));
                bool sgt = key > o;
                key = (sgt != takeMin) ? key : o;
            }
        }
        if (lane >= 44) {
            int m = 1023 - (int)(unsigned)(key & 0xFFFFFFFFu);
            idx[row * KNN + (63 - lane)] = m;
        }
    } else {
        for (int kk = 0; kk < KNN; kk++) {
            float bv = v[0]; int bj = 0;
            #pragma unroll
            for (int j = 1; j < 16; j++) if (v[j] > bv) { bv = v[j]; bj = j; }
            int bi = lane * 16 + bj;
            for (int d = 32; d > 0; d >>= 1) {
                float ov = __shfl_down(bv, d, 64);
                int oi = __shfl_down(bi, d, 64);
                if (ov > bv || (ov == bv && oi < bi)) { bv = ov; bi = oi; }
            }
            bi = __shfl(bi, 0, 64);
            if ((bi >> 4) == lane) {
                #pragma unroll
                for (int j = 0; j < 16; j++) if (j == (bi & 15)) v[j] = -INFINITY;
            }
            if (lane == 0) idx[row * KNN + kk] = bi;
        }
    }
}

// ---------------- gmax: LDS-staged gather-max + BN + lrelu ----------------
__global__ void __launch_bounds__(256)
gmax_kernel(const float* __restrict__ A, const float* __restrict__ Bv,
            const int* __restrict__ idx, const float* __restrict__ bnp,
            float* __restrict__ out, int Cout, int outStrideB) {
    int b = blockIdx.z;
    int n0 = blockIdx.x * 64;
    int o0 = blockIdx.y * 4;
    int tid = threadIdx.x;
    __shared__ int sidx[64 * 21];
    __shared__ float sA[4][N_PTS];
    for (int t = tid; t < 64 * KNN; t += 256) {
        int nl = t / KNN, k = t - nl * KNN;
        sidx[nl * 21 + k] = idx[(b * N_PTS + n0) * KNN + t];
    }
    const float* Abase = A + ((size_t)b * Cout + o0) * N_PTS;
    for (int q = 0; q < 4; q++) {
        int f = q * 256 + tid;
        int r = f >> 8, c4 = (f & 255) * 4;
        *(float4*)&sA[r][c4] = *(const float4*)&Abase[(size_t)r * N_PTS + c4];
    }
    __syncthreads();
    int nl = tid & 63, ol = tid >> 6;
    float best = -INFINITY;
    #pragma unroll
    for (int k = 0; k < KNN; k++) {
        int j = sidx[nl * 21 + k];
        best = fmaxf(best, sA[ol][j]);
    }
    int o = o0 + ol;
    int n = n0 + nl;
    float pre = best + Bv[((size_t)b * Cout + o) * N_PTS + n];
    float g = bnp[o], bb = bnp[Cout + o], m = bnp[2 * Cout + o], vv = bnp[3 * Cout + o];
    float scale = g / sqrtf(vv + EPSB);
    out[(size_t)b * outStrideB + (size_t)o * N_PTS + n] = lrelu((pre - m) * scale + bb);
}

// ---------------- cat fp32 [b][c][n] -> catT bf16 [b][n][c] ----------------
__global__ void catT_kernel(const float* __restrict__ cat, ushort_t* __restrict__ catT) {
    int b = blockIdx.z, ct = blockIdx.y, nt = blockIdx.x;
    int tid = threadIdx.x;
    __shared__ float tile[64][65];
    const float* cb = cat + (size_t)b * 512 * N_PTS;
    for (int q = 0; q < 16; q++) {
        int e = q * 256 + tid;
        int c = e >> 6, n = e & 63;
        tile[c][n] = cb[(size_t)(ct * 64 + c) * N_PTS + nt * 64 + n];
    }
    __syncthreads();
    for (int q = 0; q < 16; q++) {
        int e = q * 256 + tid;
        int n = e >> 6, c = e & 63;
        catT[((size_t)b * N_PTS + nt * 64 + n) * 512 + ct * 64 + c] = f2bf(tile[c][n]);
    }
}

// ---------------- embedding GEMM (bf16 MFMA, glds staging) + bn + lrelu + max/sum ----------------
__global__ void __launch_bounds__(256)
gemm6_mfma(const ushort_t* __restrict__ weh, const ushort_t* __restrict__ catT,
           const float* __restrict__ bne,
           float* __restrict__ pmax, float* __restrict__ psum) {
    int b = blockIdx.z, ot = blockIdx.y, nt = blockIdx.x;
    int tid = threadIdx.x;
    int wv = tid >> 6, lane = tid & 63, q = lane >> 4, lr = lane & 15;
    int mblk = wv >> 1, nblk = wv & 1;
    int srow = lane >> 2, scol = (lane & 3) * 8;
    __shared__ __align__(16) ushort_t sA[128 * 32];
    __shared__ __align__(16) ushort_t sB[128 * 32];
    __shared__ float sa[128], sc[128];
    __shared__ float redmax[128][2], redsum[128][2];
    int o0 = ot * 128, n0 = nt * 128;
    if (tid < 128) {
        int o = o0 + tid;
        float g = bne[o], bb = bne[1024 + o], m = bne[2048 + o], vv = bne[3072 + o];
        float scale = g / sqrtf(vv + EPSB);
        sa[tid] = scale; sc[tid] = bb - m * scale;
    }
    f32x4 acc[4][4] = {};
    const ushort_t* cT = catT + (size_t)b * N_PTS * 512;
    for (int k0 = 0; k0 < 512; k0 += 32) {
        __syncthreads();
        #pragma unroll
        for (int h = 0; h < 2; h++) {
            int chunk = wv + h * 4;
            int row = chunk * 16 + srow;
            glds16(weh + (size_t)(o0 + row) * 512 + k0 + scol, sA + chunk * 512);
            glds16(cT  + (size_t)(n0 + row) * 512 + k0 + scol, sB + chunk * 512);
        }
        __syncthreads();
        short8 af[4], bfr[4];
        for (int mi = 0; mi < 4; mi++)
            af[mi] = *(const short8*)&sA[(mblk * 64 + mi * 16 + lr) * 32 + q * 8];
        for (int ni = 0; ni < 4; ni++)
            bfr[ni] = *(const short8*)&sB[(nblk * 64 + ni * 16 + lr) * 32 + q * 8];
        for (int mi = 0; mi < 4; mi++)
            for (int ni = 0; ni < 4; ni++)
                acc[mi][ni] = __builtin_amdgcn_mfma_f32_16x16x32_bf16(af[mi], bfr[ni], acc[mi][ni], 0, 0, 0);
    }
    for (int mi = 0; mi < 4; mi++) {
        for (int r = 0; r < 4; r++) {
            int row = mblk * 64 + mi * 16 + q * 4 + r;
            float a = sa[row], c = sc[row];
            float mx = -INFINITY, sm = 0.f;
            for (int ni = 0; ni < 4; ni++) {
                float y = lrelu(acc[mi][ni][r] * a + c);
                mx = fmaxf(mx, y); sm += y;
            }
            for (int msk = 1; msk < 16; msk <<= 1) {
                mx = fmaxf(mx, __shfl_xor(mx, msk, 16));
                sm += __shfl_xor(sm, msk, 16);
            }
            if (lr == 0) { redmax[row][nblk] = mx; redsum[row][nblk] = sm; }
        }
    }
    __syncthreads();
    if (tid < 128) {
        float mx = fmaxf(redmax[tid][0], redmax[tid][1]);
        float sm = redsum[tid][0] + redsum[tid][1];
        int o = o0 + tid;
        pmax[((size_t)(b * 1024 + o)) * 8 + nt] = mx;
        psum[((size_t)(b * 1024 + o)) * 8 + nt] = sm;
    }
}

__global__ void pool_reduce_kernel(const float* __restrict__ pmax, const float* __restrict__ psum,
                                   float* __restrict__ h0) {
    int g = blockIdx.x * 256 + threadIdx.x;  // b*1024 + o
    int b = g >> 10, o = g & 1023;
    float mx = -INFINITY, sm = 0.f;
    for (int t = 0; t < 8; t++) { mx = fmaxf(mx, pmax[g * 8 + t]); sm += psum[g * 8 + t]; }
    h0[(size_t)b * 2048 + o] = mx;
    h0[(size_t)b * 2048 + 1024 + o] = sm * (1.0f / 1024.0f);
}

// ---------------- FC: one wave per output ----------------
__global__ void fc_kernel(const float* __restrict__ in, const float* __restrict__ w,
                          const float* __restrict__ bnp, const float* __restrict__ bias,
                          float* __restrict__ out, int Cin, int Cout, int mode) {
    int blk = blockIdx.x;  // b*Cout + o
    int b = blk / Cout, o = blk % Cout;
    int lane = threadIdx.x;
    const float* inb = in + (size_t)b * Cin;
    const float* wo = w + (size_t)o * Cin;
    float acc = 0.f;
    for (int c = lane; c < Cin; c += 64) acc += inb[c] * wo[c];
    for (int s = 32; s > 0; s >>= 1) acc += __shfl_down(acc, s, 64);
    if (lane == 0) {
        float y = acc;
        if (mode == 0) {
            float g = bnp[o], bb = bnp[Cout + o], m = bnp[2 * Cout + o], vv = bnp[3 * Cout + o];
            y = lrelu((y - m) * (g / sqrtf(vv + EPSB)) + bb);
        } else {
            y += bias[o];
        }
        out[(size_t)b * Cout + o] = y;
    }
}

extern "C" void kernel_launch(void* const* d_in, const int* in_sizes, int n_in,
                              void* d_out, int out_size, void* d_ws, size_t ws_size,
                              hipStream_t stream) {
    const float* x    = (const float*)d_in[0];
    const float* w0   = (const float*)d_in[1];
    const float* w1   = (const float*)d_in[2];
    const float* w2   = (const float*)d_in[3];
    const float* w3   = (const float*)d_in[4];
    const float* bn0  = (const float*)d_in[5];
    const float* bn1  = (const float*)d_in[6];
    const float* bn2  = (const float*)d_in[7];
    const float* bn3  = (const float*)d_in[8];
    const float* we   = (const float*)d_in[9];
    const float* bne  = (const float*)d_in[10];
    const float* wf0  = (const float*)d_in[11];
    const float* bnf0 = (const float*)d_in[12];
    const float* wf1  = (const float*)d_in[13];
    const float* bnf1 = (const float*)d_in[14];
    const float* wfin = (const float*)d_in[15];
    const float* bfin = (const float*)d_in[16];

    float* ws = (float*)d_ws;
    size_t off = 0;
    float* cat  = ws + off; off += (size_t)BATCH * 512 * N_PTS;        // 16 MB
    float* pd   = ws + off; off += (size_t)BATCH * N_PTS * N_PTS;      // 33.5 MB
    float* A    = ws + off; off += (size_t)BATCH * 256 * N_PTS;        // 8 MB (disjoint from pd)
    float* Bv   = ws + off; off += (size_t)BATCH * 256 * N_PTS;        // 8 MB
    float* pmax = ws + off; off += (size_t)BATCH * N_PTS * 8;
    float* psum = ws + off; off += (size_t)BATCH * N_PTS * 8;
    float* h0   = ws + off; off += (size_t)BATCH * 2048;
    float* h1   = ws + off; off += (size_t)BATCH * 512;
    float* h2   = ws + off; off += (size_t)BATCH * 256;
    float* xxv  = ws + off; off += (size_t)BATCH * N_PTS;
    int*   idx  = (int*)(ws + off); off += (size_t)BATCH * N_PTS * KNN;
    ushort_t* weh  = (ushort_t*)(ws + off); off += (size_t)(1024 * 512) / 2;        // 1 MB
    ushort_t* catT = (ushort_t*)(ws + off); off += (size_t)BATCH * N_PTS * 512 / 2; // 8 MB
    ushort_t* xT3  = (ushort_t*)(ws + off); off += (size_t)BATCH * N_PTS * 3 * 128 / 2; // max C=128
    ushort_t* Wext1 = (ushort_t*)(ws + off); off += (size_t)(128 * 3 * 64) / 2;
    ushort_t* Wext2 = (ushort_t*)(ws + off); off += (size_t)(256 * 3 * 64) / 2;
    ushort_t* Wext3 = (ushort_t*)(ws + off); off += (size_t)(512 * 3 * 128) / 2;
    float* wpt0 = ws + off; off += 3 * 128;

    const int CSTR = 512 * N_PTS;   // cat batch stride
    const int topkBlocks = BATCH * N_PTS / 4;

    // ---- all weight prep in one launch
    prep_kernel<<<866, 256, 0, stream>>>(we, weh, w0, wpt0, w1, Wext1, w2, Wext2, w3, Wext3);

    // ---- block 0: input x (B,3,N), C=3 -> Cout=64, out ch [0,64)  (VALU path)
    pdabv_valu<<<dim3(9, 8, BATCH), 256, 0, stream>>>(x, wpt0, pd, A, Bv, 3, 64, 3 * N_PTS);
    topk_kernel<<<topkBlocks, 256, 0, stream>>>(pd, idx);
    gmax_kernel<<<dim3(16, 16, BATCH), 256, 0, stream>>>(A, Bv, idx, bn0, cat, 64, CSTR);

    // ---- block 1: C=64 -> Cout=64, out ch [64,128)  (MFMA bf16x3 + glds)
    split_kernel<<<dim3(16, 1, BATCH), 256, 0, stream>>>(cat, xT3, xxv, 64, CSTR);
    pdabv_mfma<<<dim3(8, 9, BATCH), 256, 0, stream>>>(xT3, Wext1, xxv, pd, A, Bv, 64, 6, 64);
    topk_kernel<<<topkBlocks, 256, 0, stream>>>(pd, idx);
    gmax_kernel<<<dim3(16, 16, BATCH), 256, 0, stream>>>(A, Bv, idx, bn1, cat + 64 * N_PTS, 64, CSTR);

    // ---- block 2: C=64 -> Cout=128, out ch [128,256)
    split_kernel<<<dim3(16, 1, BATCH), 256, 0, stream>>>(cat + 64 * N_PTS, xT3, xxv, 64, CSTR);
    pdabv_mfma<<<dim3(8, 10, BATCH), 256, 0, stream>>>(xT3, Wext2, xxv, pd, A, Bv, 64, 6, 128);
    topk_kernel<<<topkBlocks, 256, 0, stream>>>(pd, idx);
    gmax_kernel<<<dim3(16, 32, BATCH), 256, 0, stream>>>(A, Bv, idx, bn2, cat + 128 * N_PTS, 128, CSTR);

    // ---- block 3: C=128 -> Cout=256, out ch [256,512)
    split_kernel<<<dim3(16, 1, BATCH), 256, 0, stream>>>(cat + 128 * N_PTS, xT3, xxv, 128, CSTR);
    pdabv_mfma<<<dim3(8, 12, BATCH), 256, 0, stream>>>(xT3, Wext3, xxv, pd, A, Bv, 128, 7, 256);
    topk_kernel<<<topkBlocks, 256, 0, stream>>>(pd, idx);
    gmax_kernel<<<dim3(16, 64, BATCH), 256, 0, stream>>>(A, Bv, idx, bn3, cat + 256 * N_PTS, 256, CSTR);

    // ---- cat -> bf16 transposed, then MFMA embedding + pooling
    catT_kernel<<<dim3(16, 8, BATCH), 256, 0, stream>>>(cat, catT);
    gemm6_mfma<<<dim3(8, 8, BATCH), 256, 0, stream>>>(weh, catT, bne, pmax, psum);
    pool_reduce_kernel<<<32, 256, 0, stream>>>(pmax, psum, h0);

    // ---- FC head
    fc_kernel<<<BATCH * 512, 64, 0, stream>>>(h0, wf0, bnf0, nullptr, h1, 2048, 512, 0);
    fc_kernel<<<BATCH * 256, 64, 0, stream>>>(h1, wf1, bnf1, nullptr, h2, 512, 256, 0);
    fc_kernel<<<BATCH * 64, 64, 0, stream>>>(h2, wfin, nullptr, bfin, (float*)d_out, 256, 64, 1);
}